// Round 11
// baseline (16710.725 us; speedup 1.0000x reference)
//
#include <hip/hip_runtime.h>
#include <hip/hip_fp16.h>

#define H 1024
#define V 32000
#define STEPS 375
#define NB1 256       // gru blocks
#define NB2 1024      // logits blocks (4 per CU)
#define RPB1 125      // out cols per gru block
#define DELTA 0.02f   // f16->fp32 rescue margin (>=100x the 5-sigma f16 dot error)

typedef _Float16 half2v __attribute__((ext_vector_type(2)));

__device__ __forceinline__ float dot4(const float4 a, const float4 b) {
    return fmaf(a.x, b.x, fmaf(a.y, b.y, fmaf(a.z, b.z, a.w * b.w)));
}

__device__ __forceinline__ float wave_sum(float v) {
#pragma unroll
    for (int off = 32; off > 0; off >>= 1) v += __shfl_xor(v, off);
    return v;
}

__device__ __forceinline__ void sm_merge(float& m, float& ss, int& a,
                                         float om, float os, int oa) {
    if (om > m || (om == m && oa < a)) {
        ss = os + ss * expf(m - om); m = om; a = oa;
    } else {
        ss += os * expf(om - m);
    }
}

// dot of packed-f16 pair (in u32) with half2, accumulate into c
__device__ __forceinline__ float fdot2u(unsigned u, half2v h, float c) {
#if __has_builtin(__builtin_amdgcn_fdot2)
    return __builtin_amdgcn_fdot2(__builtin_bit_cast(half2v, u), h, c, false);
#else
    half2v w = __builtin_bit_cast(half2v, u);
    return fmaf((float)w.y, (float)h.y, fmaf((float)w.x, (float)h.x, c));
#endif
}

// ---------------- init: h0 = enc ----------------
__global__ void init_kernel(const float* __restrict__ enc, float* __restrict__ h0) {
    for (int i = threadIdx.x; i < H; i += 256) h0[i] = enc[i];
}

// ---------------- one-time: lin_W fp32 -> packed f16 ----------------
__global__ __launch_bounds__(512) void conv_kernel(const float* __restrict__ src,
                                                   unsigned short* __restrict__ dst) {
    const size_t idx = (size_t)blockIdx.x * 512 + threadIdx.x;  // 4,096,000 total
    const float4* s4 = (const float4*)src;
    float4 a = s4[2 * idx], b = s4[2 * idx + 1];
    uint4 o;
    o.x = (unsigned)__half_as_ushort(__float2half(a.x)) |
          ((unsigned)__half_as_ushort(__float2half(a.y)) << 16);
    o.y = (unsigned)__half_as_ushort(__float2half(a.z)) |
          ((unsigned)__half_as_ushort(__float2half(a.w)) << 16);
    o.z = (unsigned)__half_as_ushort(__float2half(b.x)) |
          ((unsigned)__half_as_ushort(__float2half(b.y)) << 16);
    o.w = (unsigned)__half_as_ushort(__float2half(b.z)) |
          ((unsigned)__half_as_ushort(__float2half(b.w)) << 16);
    ((uint4*)dst)[idx] = o;
}

// ---------------- per-step GRU (argmax feedback; out[s-1] -= logZ) -------------
__global__ __launch_bounds__(256) void gru_kernel(
    const float* __restrict__ emb, const float* __restrict__ W_ih,
    const float* __restrict__ W_hh, const float* __restrict__ b_ih,
    const float* __restrict__ b_hh, const float* __restrict__ h_cur,
    float* __restrict__ h_next, float* __restrict__ out_prev,
    const float* __restrict__ pm, const float* __restrict__ ps,
    const int* __restrict__ pa, int s) {
    const int tid = threadIdx.x;
    const int lane = tid & 63;
    const int wv = tid >> 6;
    const int b = blockIdx.x;

    int tok = 0;
    if (s > 0) {
        float m = -3.4e38f, ss = 0.f;
        int a = 0x7fffffff;
#pragma unroll
        for (int k = 0; k < NB2 / 64; ++k)
            sm_merge(m, ss, a, pm[k * 64 + lane], ps[k * 64 + lane], pa[k * 64 + lane]);
#pragma unroll
        for (int off = 32; off > 0; off >>= 1) {
            float om = __shfl_xor(m, off), os = __shfl_xor(ss, off);
            int oa = __shfl_xor(a, off);
            sm_merge(m, ss, a, om, os, oa);
        }
        const float logZ = m + logf(ss);
        tok = a;
        if (tid < RPB1) out_prev[b * RPB1 + tid] -= logZ;
    }

    const int i = b * 4 + wv;   // GRU output row (4 waves, one row each)
    const float4* xp = (const float4*)(emb + (size_t)tok * H);
    const float4* hp = (const float4*)h_cur;
    float4 xv[4], hv[4];
#pragma unroll
    for (int j = 0; j < 4; ++j) {
        xv[j] = xp[lane + 64 * j];
        hv[j] = hp[lane + 64 * j];
    }
    const float4* wx0 = (const float4*)(W_ih + (size_t)i * H);
    const float4* wx1 = (const float4*)(W_ih + ((size_t)i + H) * H);
    const float4* wx2 = (const float4*)(W_ih + ((size_t)i + 2 * H) * H);
    const float4* wh0 = (const float4*)(W_hh + (size_t)i * H);
    const float4* wh1 = (const float4*)(W_hh + ((size_t)i + H) * H);
    const float4* wh2 = (const float4*)(W_hh + ((size_t)i + 2 * H) * H);
    float4 WX0[4], WX1[4], WX2[4], WH0[4], WH1[4], WH2[4];
#pragma unroll
    for (int j = 0; j < 4; ++j) {
        const int idx = lane + 64 * j;
        WX0[j] = wx0[idx]; WX1[j] = wx1[idx]; WX2[j] = wx2[idx];
        WH0[j] = wh0[idx]; WH1[j] = wh1[idx]; WH2[j] = wh2[idx];
    }
    float sx0 = 0, sx1 = 0, sx2 = 0, sh0 = 0, sh1 = 0, sh2 = 0;
#pragma unroll
    for (int j = 0; j < 4; ++j) {
        sx0 += dot4(WX0[j], xv[j]); sx1 += dot4(WX1[j], xv[j]); sx2 += dot4(WX2[j], xv[j]);
        sh0 += dot4(WH0[j], hv[j]); sh1 += dot4(WH1[j], hv[j]); sh2 += dot4(WH2[j], hv[j]);
    }
    sx0 = wave_sum(sx0); sx1 = wave_sum(sx1); sx2 = wave_sum(sx2);
    sh0 = wave_sum(sh0); sh1 = wave_sum(sh1); sh2 = wave_sum(sh2);
    if (lane == 0) {
        const float rg = 1.f / (1.f + expf(-((sx0 + b_ih[i]) + (sh0 + b_hh[i]))));
        const float zg = 1.f / (1.f + expf(-((sx1 + b_ih[i + H]) + (sh1 + b_hh[i + H]))));
        const float ng = tanhf((sx2 + b_ih[i + 2 * H]) + rg * (sh2 + b_hh[i + 2 * H]));
        h_next[i] = (1.f - zg) * ng + zg * h_cur[i];
    }
}

// ------------- per-step logits: f16 GEMV (v_dot2) + fp32 rescue ---------------
// 1024 blocks x 256 threads (4 waves); 8 rows/wave, all loads batched (256 B/lane)
__global__ __launch_bounds__(256, 4) void logits_f16_kernel(
    const unsigned short* __restrict__ wh16, const float* __restrict__ lin_W,
    const float* __restrict__ lin_b, const float* __restrict__ h_src,
    float* __restrict__ orow, float* __restrict__ pm, float* __restrict__ ps,
    int* __restrict__ pa) {
    const int tid = threadIdx.x;
    const int lane = tid & 63;
    const int wv = tid >> 6;   // 0..3
    const int b = blockIdx.x;
    const int row0 = (b < 256) ? 32 * b : 8192 + 31 * (b - 256);
    const int nrows = (b < 256) ? 32 : 31;

    __shared__ float red_m[4], red_s[4];
    __shared__ float s_cm[4];
    __shared__ int s_ca[4];

    // h as half2 fragments matching the f16 row layout:
    // lane covers elems [8l..8l+7] (chunk A) and [512+8l..512+8l+7] (chunk B)
    const float4* h4 = (const float4*)h_src;
    const float4 fa0 = h4[2 * lane], fa1 = h4[2 * lane + 1];
    const float4 fb0 = h4[128 + 2 * lane], fb1 = h4[129 + 2 * lane];
    half2v ha[4], hb[4];
    ha[0] = half2v{(_Float16)fa0.x, (_Float16)fa0.y};
    ha[1] = half2v{(_Float16)fa0.z, (_Float16)fa0.w};
    ha[2] = half2v{(_Float16)fa1.x, (_Float16)fa1.y};
    ha[3] = half2v{(_Float16)fa1.z, (_Float16)fa1.w};
    hb[0] = half2v{(_Float16)fb0.x, (_Float16)fb0.y};
    hb[1] = half2v{(_Float16)fb0.z, (_Float16)fb0.w};
    hb[2] = half2v{(_Float16)fb1.x, (_Float16)fb1.y};
    hb[3] = half2v{(_Float16)fb1.z, (_Float16)fb1.w};

    // load all 8 rows' weights first (16 uint4 = 256 B/lane outstanding)
    uint4 qa[8], qb[8];
    bool val[8];
#pragma unroll
    for (int k = 0; k < 8; ++k) {
        const int rr = wv + 4 * k;
        val[k] = rr < nrows;
        const uint4* wp = (const uint4*)(wh16 + (size_t)(row0 + (val[k] ? rr : 0)) * H);
        qa[k] = wp[lane];
        qb[k] = wp[64 + lane];
    }
    __builtin_amdgcn_sched_barrier(0);

    float lg[8];
    float m = -3.4e38f, ssum = 0.f;
#pragma unroll
    for (int k = 0; k < 8; ++k) {
        float a = 0.f;
        a = fdot2u(qa[k].x, ha[0], a);
        a = fdot2u(qa[k].y, ha[1], a);
        a = fdot2u(qa[k].z, ha[2], a);
        a = fdot2u(qa[k].w, ha[3], a);
        a = fdot2u(qb[k].x, hb[0], a);
        a = fdot2u(qb[k].y, hb[1], a);
        a = fdot2u(qb[k].z, hb[2], a);
        a = fdot2u(qb[k].w, hb[3], a);
        a = wave_sum(a);
        if (val[k]) {
            const int col = row0 + wv + 4 * k;
            a += lin_b[col];
            lg[k] = a;
            if (lane == 0) __builtin_nontemporal_store(a, &orow[col]);
            if (a > m) { ssum *= expf(m - a); m = a; }
            ssum += expf(a - m);
        } else {
            lg[k] = -3.4e38f;
        }
    }
    if (lane == 0) { red_m[wv] = m; red_s[wv] = ssum; }
    __syncthreads();

    // block f16 max
    float Mb = fmaxf(fmaxf(red_m[0], red_m[1]), fmaxf(red_m[2], red_m[3]));

    // fp32 rescue of candidate rows (wave-uniform predicate; ~1-2 per block)
    float cm = -3.4e38f;
    int ca = 0x7fffffff;
    float4 hv[4];
    bool loaded = false;
#pragma unroll
    for (int k = 0; k < 8; ++k) {
        if (lg[k] > Mb - DELTA) {
            const int row = row0 + wv + 4 * k;
            if (!loaded) {
#pragma unroll
                for (int j = 0; j < 4; ++j) hv[j] = h4[lane + 64 * j];
                loaded = true;
            }
            const float4* rp = (const float4*)(lin_W + (size_t)row * H);
            float a = 0.f;
#pragma unroll
            for (int j = 0; j < 4; ++j) a += dot4(rp[lane + 64 * j], hv[j]);
            a = wave_sum(a) + lin_b[row];
            if (a > cm || (a == cm && row < ca)) { cm = a; ca = row; }
        }
    }
    if (lane == 0) { s_cm[wv] = cm; s_ca[wv] = ca; }
    __syncthreads();
    if (tid == 0) {
        float M = red_m[0], S = red_s[0];
#pragma unroll
        for (int w = 1; w < 4; ++w) {   // merge sums
            const float mw = red_m[w], sw = red_s[w];
            if (mw > M) { S = sw + S * expf(M - mw); M = mw; }
            else S += sw * expf(mw - M);
        }
        float CM = s_cm[0];
        int CA = s_ca[0];
#pragma unroll
        for (int w = 1; w < 4; ++w)
            if (s_cm[w] > CM || (s_cm[w] == CM && s_ca[w] < CA)) { CM = s_cm[w]; CA = s_ca[w]; }
        pm[b] = CM;                    // fp32-exact block max (argmax-safe)
        ps[b] = S * expf(M - CM);      // f16 sumexp re-anchored to CM
        pa[b] = CA;
    }
}

// ---------------- fallback fp32 logits (if ws too small for f16 copy) ---------
__global__ __launch_bounds__(256, 4) void logits_fp32_kernel(
    const float* __restrict__ lin_W, const float* __restrict__ lin_b,
    const float* __restrict__ h_src, float* __restrict__ orow,
    float* __restrict__ pm, float* __restrict__ ps, int* __restrict__ pa) {
    const int tid = threadIdx.x;
    const int lane = tid & 63;
    const int wv = tid >> 6;
    const int b = blockIdx.x;
    const int row0 = (b < 256) ? 32 * b : 8192 + 31 * (b - 256);
    const int nrows = (b < 256) ? 32 : 31;

    __shared__ float red_m[4], red_s[4];
    __shared__ int red_a[4];

    const float4* h4 = (const float4*)h_src;
    float4 hr[4];
#pragma unroll
    for (int j = 0; j < 4; ++j) hr[j] = h4[lane + 64 * j];

    float m = -3.4e38f, ssum = 0.f;
    int arg = 0x7fffffff;
#pragma unroll
    for (int half = 0; half < 2; ++half) {
        float4 w[4][4];
        int rr[4];
        bool val[4];
#pragma unroll
        for (int q = 0; q < 4; ++q) {
            rr[q] = wv + 4 * (half * 4 + q);
            val[q] = rr[q] < nrows;
            const float4* p = (const float4*)(lin_W + (size_t)(row0 + (val[q] ? rr[q] : 0)) * H);
#pragma unroll
            for (int j = 0; j < 4; ++j) w[q][j] = p[lane + 64 * j];
        }
        __builtin_amdgcn_sched_barrier(0);
#pragma unroll
        for (int q = 0; q < 4; ++q) {
            float a = 0.f;
#pragma unroll
            for (int j = 0; j < 4; ++j) a += dot4(w[q][j], hr[j]);
            a = wave_sum(a);
            if (val[q]) {
                const int col = row0 + rr[q];
                a += lin_b[col];
                if (lane == 0) __builtin_nontemporal_store(a, &orow[col]);
                if (a > m) { ssum *= expf(m - a); m = a; arg = col; }
                ssum += expf(a - m);
            }
        }
    }
    if (lane == 0) { red_m[wv] = m; red_s[wv] = ssum; red_a[wv] = arg; }
    __syncthreads();
    if (tid == 0) {
        float M = red_m[0], S = red_s[0];
        int A = red_a[0];
#pragma unroll
        for (int w = 1; w < 4; ++w) sm_merge(M, S, A, red_m[w], red_s[w], red_a[w]);
        pm[b] = M; ps[b] = S; pa[b] = A;
    }
}

// ---------------- tail: finalize out[STEPS-1] + write h_final ----------------
__global__ __launch_bounds__(256) void tail_kernel(
    float* __restrict__ out_last, const float* __restrict__ pm,
    const float* __restrict__ ps, const int* __restrict__ pa,
    const float* __restrict__ h_final, float* __restrict__ out_h) {
    const int tid = threadIdx.x;
    const int lane = tid & 63;
    const int b = blockIdx.x;
    float m = -3.4e38f, ss = 0.f;
    int a = 0x7fffffff;
#pragma unroll
    for (int k = 0; k < NB2 / 64; ++k)
        sm_merge(m, ss, a, pm[k * 64 + lane], ps[k * 64 + lane], pa[k * 64 + lane]);
#pragma unroll
    for (int off = 32; off > 0; off >>= 1) {
        float om = __shfl_xor(m, off), os = __shfl_xor(ss, off);
        int oa = __shfl_xor(a, off);
        sm_merge(m, ss, a, om, os, oa);
    }
    const float logZ = m + logf(ss);
    if (tid < RPB1) out_last[b * RPB1 + tid] -= logZ;
    if (b == 0)
        for (int i = tid; i < H; i += 256) out_h[i] = h_final[i];
}

extern "C" void kernel_launch(void* const* d_in, const int* in_sizes, int n_in,
                              void* d_out, int out_size, void* d_ws, size_t ws_size,
                              hipStream_t stream) {
    const float* enc = (const float*)d_in[0];
    const float* emb = (const float*)d_in[1];
    const float* W_ih = (const float*)d_in[2];
    const float* W_hh = (const float*)d_in[3];
    const float* b_ih = (const float*)d_in[4];
    const float* b_hh = (const float*)d_in[5];
    const float* lin_W = (const float*)d_in[6];
    const float* lin_b = (const float*)d_in[7];
    float* out = (float*)d_out;
    float* ws = (float*)d_ws;

    // ws: h_buf[2][H] | pm[NB2] | ps[NB2] | pa[NB2](int) | pad-to-32KB | wh16
    float* h_buf = ws;
    float* pm = ws + 2 * H;
    float* ps = pm + NB2;
    int* pa = (int*)(ps + NB2);
    unsigned short* wh16 = (unsigned short*)((char*)d_ws + 32768);
    const size_t need = 32768 + (size_t)V * H * 2;
    const bool f16path = ws_size >= need;

    init_kernel<<<1, 256, 0, stream>>>(enc, h_buf);
    if (f16path)
        conv_kernel<<<V * H / 8 / 512, 512, 0, stream>>>(lin_W, wh16);
    for (int s = 0; s < STEPS; ++s) {
        float* h_cur = h_buf + (s & 1) * H;
        float* h_next = h_buf + ((s + 1) & 1) * H;
        float* out_prev = out + (size_t)(s > 0 ? s - 1 : 0) * V;
        gru_kernel<<<NB1, 256, 0, stream>>>(emb, W_ih, W_hh, b_ih, b_hh,
                                            h_cur, h_next, out_prev,
                                            pm, ps, pa, s);
        if (f16path)
            logits_f16_kernel<<<NB2, 256, 0, stream>>>(wh16, lin_W, lin_b, h_next,
                                                       out + (size_t)s * V, pm, ps, pa);
        else
            logits_fp32_kernel<<<NB2, 256, 0, stream>>>(lin_W, lin_b, h_next,
                                                        out + (size_t)s * V, pm, ps, pa);
    }
    tail_kernel<<<NB1, 256, 0, stream>>>(out + (size_t)(STEPS - 1) * V, pm, ps, pa,
                                         h_buf + (STEPS & 1) * H,
                                         out + (size_t)V * STEPS);
}